// Round 10
// baseline (164.243 us; speedup 1.0000x reference)
//
#include <hip/hip_runtime.h>
#include <hip/hip_bf16.h>
#include <math.h>

typedef unsigned short u16;
typedef _Float16 f16x8 __attribute__((ext_vector_type(8)));
typedef float    f32x16 __attribute__((ext_vector_type(16)));
typedef u16      u16x8  __attribute__((ext_vector_type(8)));
typedef u16      u16x4  __attribute__((ext_vector_type(4)));

#define BATCH 16
#define T0 64000
#define T1 32000
#define T2 16000
#define T3 8000
#define NT3 124          // t3 outputs per block; 65 x 124 = 8060 >= 8000 (tail masked)
#define NBLKX 65
#define NROWS1 517       // y1 rows staged per block (4*NT3 + 21)
#define NLINES 259       // 128B LDS lines; 33,152 B -> 3+ blocks/CU by LDS

static __device__ __forceinline__ u16 f2h(float f) {
    _Float16 h = (_Float16)f;
    u16 u;
    __builtin_memcpy(&u, &h, 2);
    return u;
}

// ---------------- weight prep (f16, transposed) + pooled/cnt zero
// a2t[kk][g][o][j]: kk 0..8, g=0..3, o=0..63, j=0..7    18432 u16
// a3t[kk][g][o][j]: kk 0..8, g=0..7, o=0..127, j=0..7   73728 u16
__global__ __launch_bounds__(256) void prep_w_k(const float* __restrict__ w2,
                                                const float* __restrict__ w3,
                                                u16* __restrict__ a2t,
                                                u16* __restrict__ a3t,
                                                float* __restrict__ pooled,
                                                int* __restrict__ cnt) {
    int idx = blockIdx.x * 256 + threadIdx.x;
    if (idx < 18432) {
        int j = idx & 7, o = (idx >> 3) & 63, g = (idx >> 9) & 3, kk = idx >> 11;
        a2t[idx] = f2h(w2[(o * 32 + g * 8 + j) * 9 + kk]);
    } else if (idx < 18432 + 73728) {
        int jdx = idx - 18432;
        int j = jdx & 7, o = (jdx >> 3) & 127, g = (jdx >> 10) & 7, kk = jdx >> 13;
        a3t[jdx] = f2h(w3[(o * 64 + g * 8 + j) * 9 + kk]);
    } else if (idx < 18432 + 73728 + 2048) {
        pooled[idx - 18432 - 73728] = 0.f;
    } else if (idx < 18432 + 73728 + 2048 + 16) {
        cnt[idx - 18432 - 73728 - 2048] = 0;
    }
}

// ---------------- mega half-tile @ 3 blocks/CU: conv1(scalar) -> conv2(MFMA, single
//                  chunk, in-place LDS) -> conv3(MFMA)+pool -> feats tail
// OCCUPANCY retry of R5 with the two failure causes fixed:
//  - R5 failed because __launch_bounds__(512,8) = 64-reg cap; kernel needs ~75
//    combined (acc2[2]=32 AGPR + frags + addr). (512,6) = cap 85: fits, and 6
//    waves/SIMD = 3 blocks/CU = 24 waves/CU (1.5x the full-tile's 16).
//    SPILL FALSIFIER: WRITE_SIZE jumping to MBs (R5: 8.4MB). Must stay ~0.3MB.
//  - R5's 532K contended-atomic epilogue replaced by: shuffle-reduce -> 2KB LDS
//    reduce over nh -> 128 atomicAdd/block (R7 within-run A/B proved this funnel
//    size is free).
// Geometry (correctness proven by R5's passing run):
//  Phase A: scalar conv1, rows 0..516 (edge blocks 0/64 bounds-checked; interior
//    float2 loads). Phase B: single 256-lane chunk covers all 255 y2 rows; reads
//    y1 lines <= 258 (clamped) before one barrier; writes lines 0..255. Phase C:
//    M=128 x N=128 (2mh x 4nh waves of 64x32); reads lines 2*nc+kk <= 254; cols
//    nl3 >= 124 or r0+nl3 >= 8000 clamped+masked.
//  Tail: NO __threadfence (R2/R3: buffer_wbl2 = ~55us). atomics are device-scope
//    (coherent point); __syncthreads drains vmcnt(0) -> cnt increment is ordered.
__global__ __launch_bounds__(512, 6) void mega_k(const float* __restrict__ audio,
                                                 const float* __restrict__ w1,
                                                 const float* __restrict__ b1,
                                                 const u16* __restrict__ a2t,
                                                 const float* __restrict__ b2,
                                                 const u16* __restrict__ a3t,
                                                 const float* __restrict__ b3,
                                                 float* __restrict__ pooled,
                                                 int* __restrict__ cnt,
                                                 const float* __restrict__ wl,
                                                 const float* __restrict__ bl,
                                                 float* __restrict__ featbuf) {
    __shared__ u16 sm[NLINES * 64];        // 33,152 B
    const int tid = threadIdx.x;
    const int b = blockIdx.y;
    const int r0 = blockIdx.x * NT3;
    const int lane = tid & 63, wv = tid >> 6;          // wv 0..7
    const int ls = lane >> 5, ln = lane & 31;

    // ---- Phase A: scalar conv1 into LDS (y1 rows 0..516; global t1 = 4*r0-12+l1)
    {
        const float* ar = audio + (size_t)b * T0;
        const bool edge = (blockIdx.x == 0) || (blockIdx.x == NBLKX - 1);
        #pragma unroll
        for (int rep = 0; rep < 2; ++rep) {
            int l1 = rep * 512 + tid;
            if (l1 >= NROWS1) break;
            int t1 = 4 * r0 - 12 + l1;
            int rr = l1 >> 1, pp = l1 & 1;
            if (edge && (t1 < 0 || t1 >= T1)) {
                u16x8 z;
                #pragma unroll
                for (int q = 0; q < 8; ++q) z[q] = 0;
                #pragma unroll
                for (int g = 0; g < 4; ++g) {
                    int slot = (pp * 4 + g) ^ (rr & 7);
                    *(u16x8*)(sm + rr * 64 + slot * 8) = z;
                }
            } else {
                int base = 2 * t1 - 4;
                float x[9];
                if (edge) {
                    #pragma unroll
                    for (int k = 0; k < 9; ++k) {
                        int t0v = base + k;
                        x[k] = (t0v >= 0 && t0v < T0) ? ar[t0v] : 0.f;
                    }
                } else {
                    // base even -> 8B-aligned float2 loads; bit-identical values
                    const float2* p2 = (const float2*)(ar + base);
                    #pragma unroll
                    for (int q = 0; q < 4; ++q) {
                        float2 c = p2[q];
                        x[2 * q]     = c.x;
                        x[2 * q + 1] = c.y;
                    }
                    x[8] = ar[base + 8];
                }
                #pragma unroll
                for (int g = 0; g < 4; ++g) {
                    u16x8 v;
                    #pragma unroll
                    for (int j = 0; j < 8; ++j) {
                        int ch = g * 8 + j;
                        float acc = b1[ch];
                        #pragma unroll
                        for (int k = 0; k < 9; ++k) acc = fmaf(x[k], w1[ch * 9 + k], acc);
                        v[j] = f2h(fmaxf(acc, 0.f));
                    }
                    int slot = (pp * 4 + g) ^ (rr & 7);
                    *(u16x8*)(sm + rr * 64 + slot * 8) = v;
                }
            }
        }
    }
    __syncthreads();

    // ---- Phase B: conv2, single 256-lane chunk (y2 rows 0..254), in-place
    {
        const int nl = 32 * wv + ln;               // y2 row 0..255
        const int nlc = (nl < 255) ? nl : 254;     // clamp reads: line <= 258
        f32x16 acc2[2];
        #pragma unroll
        for (int mi = 0; mi < 2; ++mi)
            #pragma unroll
            for (int q = 0; q < 16; ++q) acc2[mi][q] = 0.f;
        #pragma unroll 1
        for (int kk = 0; kk < 9; ++kk) {
            const int rr = nlc + (kk >> 1);
            const int pp = kk & 1;
            const u16* ap = a2t + kk * 2048;
            #pragma unroll
            for (int step = 0; step < 2; ++step) {
                int slot = (pp * 4 + 2 * step + ls) ^ (rr & 7);
                f16x8 bfB = *(const f16x8*)(sm + rr * 64 + slot * 8);
                f16x8 af0 = *(const f16x8*)(ap + (2 * step + ls) * 512 + ln * 8);
                f16x8 af1 = *(const f16x8*)(ap + (2 * step + ls) * 512 + (32 + ln) * 8);
                acc2[0] = __builtin_amdgcn_mfma_f32_32x32x16_f16(af0, bfB, acc2[0], 0, 0, 0);
                acc2[1] = __builtin_amdgcn_mfma_f32_32x32x16_f16(af1, bfB, acc2[1], 0, 0, 0);
            }
        }
        __syncthreads();                    // all y1 reads done before overwrite
        {
            int t2 = 2 * r0 - 4 + nl;
            bool valid = (t2 >= 0) && (t2 < T2) && (nl < 255);
            #pragma unroll
            for (int mi = 0; mi < 2; ++mi)
                #pragma unroll
                for (int q = 0; q < 4; ++q) {
                    u16x4 v;
                    #pragma unroll
                    for (int d = 0; d < 4; ++d) {
                        int o = 32 * mi + 8 * q + 4 * ls + d;
                        float xv = valid ? fmaxf(acc2[mi][4 * q + d] + b2[o], 0.f) : 0.f;
                        v[d] = f2h(xv);
                    }
                    int gy = 4 * mi + q;
                    int sy = gy ^ ((nl >> 1) & 7);
                    *(u16x4*)(sm + nl * 64 + sy * 8 + ls * 4) = v;
                }
        }
        __syncthreads();
    }

    // ---- Phase C: conv3 MFMA (M=128 out-ch x N=128 cols; 2mh x 4nh waves of 64x32)
    const int mh = wv & 1, nh = wv >> 1;
    const int nl3 = 32 * nh + ln;                  // t3 col 0..127
    const int nc = (nl3 < NT3) ? nl3 : NT3 - 1;    // clamp addresses: line <= 254
    f32x16 acc3[2];
    #pragma unroll
    for (int mi = 0; mi < 2; ++mi)
        #pragma unroll
        for (int q = 0; q < 16; ++q) acc3[mi][q] = 0.f;

    #pragma unroll 1
    for (int kk = 0; kk < 9; ++kk) {
        const u16* ap = a3t + kk * 8192;
        const int l2 = 2 * nc + kk;                // <= 254
        const int rkey = (nc + (kk >> 1)) & 7;
        #pragma unroll
        for (int step = 0; step < 4; ++step) {
            int sy = (2 * step + ls) ^ rkey;
            f16x8 bfv = *(const f16x8*)(sm + l2 * 64 + sy * 8);
            f16x8 af0 = *(const f16x8*)(ap + (2 * step + ls) * 1024 + (64 * mh + ln) * 8);
            f16x8 af1 = *(const f16x8*)(ap + (2 * step + ls) * 1024 + (64 * mh + 32 + ln) * 8);
            acc3[0] = __builtin_amdgcn_mfma_f32_32x32x16_f16(af0, bfv, acc3[0], 0, 0, 0);
            acc3[1] = __builtin_amdgcn_mfma_f32_32x32x16_f16(af1, bfv, acc3[1], 0, 0, 0);
        }
    }

    // epilogue: bias+relu, col mask, shuffle reduce over 32 col-lanes,
    // 2KB LDS reduce over nh, 128 atomicAdd/block (proven-free funnel size, R7)
    {
        const bool colv = (nl3 < NT3) && (r0 + nl3 < T3);
        float* red = (float*)sm;           // [4 nh][128 o] = 2 KB
        #pragma unroll
        for (int mi = 0; mi < 2; ++mi)
            #pragma unroll
            for (int r = 0; r < 16; ++r) {
                int o = 64 * mh + 32 * mi + (r & 3) + 8 * (r >> 2) + 4 * ls;
                float v = colv ? fmaxf(acc3[mi][r] + b3[o], 0.f) : 0.f;
                v += __shfl_xor(v, 1);
                v += __shfl_xor(v, 2);
                v += __shfl_xor(v, 4);
                v += __shfl_xor(v, 8);
                v += __shfl_xor(v, 16);
                if (ln == 0) red[nh * 128 + o] = v;
            }
        __syncthreads();
        if (tid < 128) {
            float s = red[tid] + red[128 + tid] + red[256 + tid] + red[384 + tid];
            atomicAdd(&pooled[b * 128 + tid], s);
        }
    }

    // ---- tail: last block of this batch computes feats (no fence; see header)
    __syncthreads();                        // drains vmcnt(0): atomics complete
    int* smi = (int*)sm;
    if (tid == 0) {
        int done = atomicAdd(&cnt[b], 1);
        smi[0] = (done == NBLKX - 1) ? 1 : 0;
    }
    __syncthreads();
    if (smi[0]) {
        float* pl = (float*)sm + 64;        // [128] pooled mean, past flag word
        float* fl = (float*)sm + 192;       // [128] feat staging
        if (tid < 128)
            pl[tid] = __hip_atomic_load(&pooled[b * 128 + tid],
                                        __ATOMIC_RELAXED, __HIP_MEMORY_SCOPE_AGENT)
                      * (1.0f / (float)T3);
        __syncthreads();
        {
            // feats matmul: all 512 threads; 4 threads per output o (i-split 32)
            int o = tid >> 2, sub = tid & 3;
            const float4* wp = (const float4*)(wl + o * 128 + sub * 32);
            const float4* pp4 = (const float4*)(pl + sub * 32);
            float s = 0.f;
            #pragma unroll
            for (int q = 0; q < 8; ++q) {
                float4 w4 = wp[q];
                float4 p4 = pp4[q];
                s += w4.x * p4.x + w4.y * p4.y + w4.z * p4.z + w4.w * p4.w;
            }
            s += __shfl_xor(s, 1);
            s += __shfl_xor(s, 2);
            if (sub == 0) fl[o] = s + bl[o];
        }
        __syncthreads();
        if (tid < 128) {
            float feat = fl[tid];
            if (tid < 64) {                 // wave 0: amps + normalize
                float r = fmaxf(feat, 0.f);
                float ssum = r;
                #pragma unroll
                for (int off = 32; off > 0; off >>= 1) ssum += __shfl_xor(ssum, off);
                featbuf[b * 128 + tid] = r / (ssum + 1e-6f);
            } else {                        // noise_mag raw
                featbuf[b * 128 + tid] = feat;
            }
        }
    }
}

// ---------------- synthesis: Chebyshev sin-recurrence, 4 samples/thread, float4 I/O
// sin(2*pi*(h+1)*u) = 2*cos(2*pi*u)*sin(2*pi*h*u) - sin(2*pi*(h-1)*u)
__global__ __launch_bounds__(256) void synth_k(const float* __restrict__ f0,
                                               const float* __restrict__ wn,
                                               const float* __restrict__ featbuf,
                                               float* __restrict__ out) {
    const int tid = threadIdx.x;
    const int b = blockIdx.y;
    __shared__ float sa[64];
    __shared__ float nm[64];
    if (tid < 64) sa[tid] = featbuf[b * 128 + tid];
    else if (tid < 128) nm[tid - 64] = featbuf[b * 128 + tid];
    __syncthreads();

    const int t0v = blockIdx.x * 1024 + tid * 4;
    if (t0v >= T0) return;                  // tail (after the barrier)

    const float4 fv = *(const float4*)(f0 + (size_t)b * T0 + t0v);
    const float4 wv = *(const float4*)(wn + (size_t)b * T0 + t0v);

    float sc[4], sp[4], tc[4], ac[4];
    #pragma unroll
    for (int s = 0; s < 4; ++s) {
        // u = f0 * t * 4/63999 (linspace incl endpoint); frac in double (phase can
        // reach ~1e5 revolutions), then recurrence runs entirely in fp32.
        double u = (double)((&fv.x)[s]) * ((double)(t0v + s) * (4.0 / 63999.0));
        float uf = (float)(u - floor(u));
        sc[s] = __builtin_amdgcn_sinf(uf);           // sin(2*pi*u)
        tc[s] = 2.0f * __builtin_amdgcn_cosf(uf);    // 2*cos(2*pi*u)
        sp[s] = 0.f;
        ac[s] = 0.f;
    }
    #pragma unroll
    for (int h = 0; h < 64; ++h) {
        float a = sa[h];
        #pragma unroll
        for (int s = 0; s < 4; ++s) {
            ac[s] = fmaf(a, sc[s], ac[s]);
            float sn = fmaf(tc[s], sc[s], -sp[s]);   // sin(2*pi*(h+2)*u)
            sp[s] = sc[s];
            sc[s] = sn;
        }
    }
    float4 o;
    #pragma unroll
    for (int s = 0; s < 4; ++s)
        (&o.x)[s] = ac[s] + (&wv.x)[s] * nm[(t0v + s) / 1000];
    *(float4*)(out + (size_t)b * T0 + t0v) = o;
}

extern "C" void kernel_launch(void* const* d_in, const int* in_sizes, int n_in,
                              void* d_out, int out_size, void* d_ws, size_t ws_size,
                              hipStream_t stream) {
    const float* audio = (const float*)d_in[0];
    const float* f0    = (const float*)d_in[1];
    const float* wn    = (const float*)d_in[2];
    const float* w1    = (const float*)d_in[3];
    const float* b1    = (const float*)d_in[4];
    const float* w2    = (const float*)d_in[5];
    const float* b2    = (const float*)d_in[6];
    const float* w3    = (const float*)d_in[7];
    const float* b3    = (const float*)d_in[8];
    const float* wl    = (const float*)d_in[9];
    const float* bl    = (const float*)d_in[10];
    float* out = (float*)d_out;

    char* ws = (char*)d_ws;
    float* pooled  = (float*)(ws);                 // 2048 f32 (zeroed by prep_w_k)
    int*   cnt     = (int*)(ws + 8192);            // 16 int (zeroed by prep_w_k)
    float* featbuf = (float*)(ws + 8448);          // 2048 f32 (written by mega tail)
    u16*   a2t     = (u16*)(ws + 16640);           // 18432 u16
    u16*   a3t     = (u16*)(ws + 16640 + 36864);   // 73728 u16

    prep_w_k<<<369, 256, 0, stream>>>(w2, w3, a2t, a3t, pooled, cnt);
    mega_k<<<dim3(NBLKX, BATCH), 512, 0, stream>>>(audio, w1, b1, a2t, b2, a3t, b3,
                                                   pooled, cnt, wl, bl, featbuf);
    synth_k<<<dim3((T0 + 1023) / 1024, BATCH), 256, 0, stream>>>(f0, wn, featbuf, out);
}

// Round 11
// 128.008 us; speedup vs baseline: 1.2831x; 1.2831x over previous
//
#include <hip/hip_runtime.h>
#include <hip/hip_bf16.h>
#include <math.h>

typedef unsigned short u16;
typedef _Float16 f16x2 __attribute__((ext_vector_type(2)));
typedef _Float16 f16x8 __attribute__((ext_vector_type(8)));
typedef float    f32x16 __attribute__((ext_vector_type(16)));
typedef u16      u16x8  __attribute__((ext_vector_type(8)));
typedef u16      u16x4  __attribute__((ext_vector_type(4)));

#define BATCH 16
#define T0 64000
#define T1 32000
#define T2 16000
#define T3 8000
#define NT3 250          // t3 outputs per mega block; 32 blocks x 250 = 8000 exactly
#define NBLKX 32
#define NROWS1 1040      // local y1 rows staged (520 LDS lines)

static __device__ __forceinline__ u16 f2h(float f) {
    _Float16 h = (_Float16)f;
    u16 u;
    __builtin_memcpy(&u, &h, 2);
    return u;
}

// ---------------- weight prep (f16, transposed) + w1 half2-pair pack + cnt zero
// a2t[kk][g][o][j]: kk 0..8, g=0..3, o=0..63, j=0..7    18432 u16
// a3t[kk][g][o][j]: kk 0..8, g=0..7, o=0..127, j=0..7   73728 u16
// w1p[ch][q]: q<4 -> (w1[ch][2q], w1[ch][2q+1]); q==4 -> (w1[ch][8], b1[ch])
//   160 half2 (fdot2 operands for Phase A; bias rides the constant-1.0 x lane)
__global__ __launch_bounds__(256) void prep_w_k(const float* __restrict__ w1,
                                                const float* __restrict__ b1,
                                                const float* __restrict__ w2,
                                                const float* __restrict__ w3,
                                                u16* __restrict__ w1p,
                                                u16* __restrict__ a2t,
                                                u16* __restrict__ a3t,
                                                int* __restrict__ cnt) {
    int idx = blockIdx.x * 256 + threadIdx.x;
    if (idx < 18432) {
        int j = idx & 7, o = (idx >> 3) & 63, g = (idx >> 9) & 3, kk = idx >> 11;
        a2t[idx] = f2h(w2[(o * 32 + g * 8 + j) * 9 + kk]);
    } else if (idx < 18432 + 73728) {
        int jdx = idx - 18432;
        int j = jdx & 7, o = (jdx >> 3) & 127, g = (jdx >> 10) & 7, kk = jdx >> 13;
        a3t[jdx] = f2h(w3[(o * 64 + g * 8 + j) * 9 + kk]);
    } else if (idx < 18432 + 73728 + 16) {
        cnt[idx - 18432 - 73728] = 0;
    } else if (idx < 18432 + 73728 + 16 + 160) {
        int j = idx - (18432 + 73728 + 16);
        int ch = j / 5, q = j % 5;
        float a = (q < 4) ? w1[ch * 9 + 2 * q]     : w1[ch * 9 + 8];
        float b = (q < 4) ? w1[ch * 9 + 2 * q + 1] : b1[ch];
        f16x2 pk;
        pk[0] = (_Float16)a;
        pk[1] = (_Float16)b;
        *(f16x2*)(w1p + 2 * j) = pk;
    }
}

// ---------------- mega: conv1(fdot2 VALU) -> conv2(MFMA, in-place LDS)
//                  -> conv3(MFMA)+pool -> feats tail (last block per batch)
// Proven-component ledger (R1..R10):
//  - Phase A conv1 via v_dot2_f32_f16 (this round): 160 fdot2 + 10 cvt + 32 f2h
//    per row vs 288 scalar FMA + 32 f2h (-37% issue in the VALU-heaviest phase).
//    f32 accumulation; only new quantization is x->f16 RTN (same class as the
//    w-f16 quantization R4 ran with unchanged absmax). Edge blocks keep the
//    exact f32 scalar path. R4 MFMA-conv1: dead (bank conflicts).
//  - Phase B: 2 chunks of 256 y2 rows at (512,2). Merged chunks (R9): 57-60us vs
//    split's tight 51; occupancy variants (R5/R10) measured worse at both (512,8)
//    (spill, WRITE_SIZE 8.4MB) and (512,6) (VGPR=32 codegen, 85us). All dead.
//  - Phase C: M=128 x N=256 (2x4 waves of 64x64), acc3[2][2].
//  - Epilogue: LDS reduce -> per-block partial slot, agent-scope relaxed stores.
//  - Tail: NO __threadfence (R2/R3: buffer_wbl2 = ~55us wall). sc1 stores hit the
//    coherent point; __syncthreads drains vmcnt(0) -> cnt inc is release-ordered.
//  - Cross-run noise ~ +/-5us on totals; only within-run deltas trustworthy.
__global__ __launch_bounds__(512, 2) void mega_k(const float* __restrict__ audio,
                                                 const float* __restrict__ w1,
                                                 const float* __restrict__ b1,
                                                 const u16* __restrict__ w1p,
                                                 const u16* __restrict__ a2t,
                                                 const float* __restrict__ b2,
                                                 const u16* __restrict__ a3t,
                                                 const float* __restrict__ b3,
                                                 float* __restrict__ partials,
                                                 int* __restrict__ cnt,
                                                 const float* __restrict__ wl,
                                                 const float* __restrict__ bl,
                                                 float* __restrict__ featbuf) {
    __shared__ u16 sm[520 * 64];           // 66,560 B -> 2 blocks/CU
    const int tid = threadIdx.x;
    const int b = blockIdx.y;
    const int r0 = blockIdx.x * NT3;
    const int lane = tid & 63, wv = tid >> 6;          // wv 0..7
    const int ls = lane >> 5, ln = lane & 31;

    // ---- Phase A: conv1 into LDS (y1 rows 0..1039; global t1 = 4*r0-12+l1)
    {
        const float* ar = audio + (size_t)b * T0;
        const bool edge = (blockIdx.x == 0) || (blockIdx.x == NBLKX - 1);
        const f16x2* wp = (const f16x2*)w1p;
        #pragma unroll
        for (int rep = 0; rep < 3; ++rep) {
            int l1 = rep * 512 + tid;
            if (l1 >= NROWS1) break;
            int t1 = 4 * r0 - 12 + l1;
            int rr = l1 >> 1, pp = l1 & 1;
            if (edge) {
                // exact f32 scalar path with zero-padding (unchanged since R1)
                if (t1 < 0 || t1 >= T1) {
                    u16x8 z;
                    #pragma unroll
                    for (int q = 0; q < 8; ++q) z[q] = 0;
                    #pragma unroll
                    for (int g = 0; g < 4; ++g) {
                        int slot = (pp * 4 + g) ^ (rr & 7);
                        *(u16x8*)(sm + rr * 64 + slot * 8) = z;
                    }
                } else {
                    int base = 2 * t1 - 4;
                    float x[9];
                    #pragma unroll
                    for (int k = 0; k < 9; ++k) {
                        int t0v = base + k;
                        x[k] = (t0v >= 0 && t0v < T0) ? ar[t0v] : 0.f;
                    }
                    #pragma unroll
                    for (int g = 0; g < 4; ++g) {
                        u16x8 v;
                        #pragma unroll
                        for (int j = 0; j < 8; ++j) {
                            int ch = g * 8 + j;
                            float acc = b1[ch];
                            #pragma unroll
                            for (int k = 0; k < 9; ++k) acc = fmaf(x[k], w1[ch * 9 + k], acc);
                            v[j] = f2h(fmaxf(acc, 0.f));
                        }
                        int slot = (pp * 4 + g) ^ (rr & 7);
                        *(u16x8*)(sm + rr * 64 + slot * 8) = v;
                    }
                }
            } else {
                // interior fast path: x -> f16 RTN pairs, v_dot2_f32_f16 accumulate
                int base = 2 * t1 - 4;                 // even -> 8B-aligned
                f16x2 xp[5];
                {
                    const float2* p2 = (const float2*)(ar + base);
                    #pragma unroll
                    for (int q = 0; q < 4; ++q) {
                        float2 c = p2[q];
                        xp[q][0] = (_Float16)c.x;
                        xp[q][1] = (_Float16)c.y;
                    }
                    float x8v = ar[base + 8];
                    xp[4][0] = (_Float16)x8v;
                    xp[4][1] = (_Float16)1.0f;         // bias lane (exact in f16)
                }
                #pragma unroll
                for (int g = 0; g < 4; ++g) {
                    f16x8 vv;
                    #pragma unroll
                    for (int jp = 0; jp < 4; ++jp) {
                        int ch0 = g * 8 + 2 * jp;
                        float a0 = 0.f, a1 = 0.f;
                        #pragma unroll
                        for (int q = 0; q < 5; ++q) {
                            a0 = __builtin_amdgcn_fdot2(xp[q], wp[ch0 * 5 + q], a0, false);
                            a1 = __builtin_amdgcn_fdot2(xp[q], wp[(ch0 + 1) * 5 + q], a1, false);
                        }
                        vv[2 * jp]     = (_Float16)fmaxf(a0, 0.f);
                        vv[2 * jp + 1] = (_Float16)fmaxf(a1, 0.f);
                    }
                    int slot = (pp * 4 + g) ^ (rr & 7);
                    *(f16x8*)(sm + rr * 64 + slot * 8) = vv;
                }
            }
        }
    }
    __syncthreads();

    // ---- Phase B: conv2 in 2 chunks of 256 y2 rows, in-place write-back
    for (int cc = 0; cc < 2; ++cc) {
        int nl = cc * 256 + 32 * wv + ln;   // this lane's y2 row (B column)
        f32x16 acc2[2];
        #pragma unroll
        for (int mi = 0; mi < 2; ++mi)
            #pragma unroll
            for (int q = 0; q < 16; ++q) acc2[mi][q] = 0.f;
        f16x8 bfB[2];
        #pragma unroll 3
        for (int kk = 0; kk < 9; ++kk) {
            {
                int rr = nl + (kk >> 1);
                int pp = kk & 1;
                #pragma unroll
                for (int step = 0; step < 2; ++step) {
                    int slot = (pp * 4 + 2 * step + ls) ^ (rr & 7);
                    bfB[step] = *(const f16x8*)(sm + rr * 64 + slot * 8);
                }
            }
            const u16* ap = a2t + kk * 2048;
            #pragma unroll
            for (int step = 0; step < 2; ++step) {
                f16x8 af0 = *(const f16x8*)(ap + (2 * step + ls) * 512 + ln * 8);
                f16x8 af1 = *(const f16x8*)(ap + (2 * step + ls) * 512 + (32 + ln) * 8);
                acc2[0] = __builtin_amdgcn_mfma_f32_32x32x16_f16(af0, bfB[step], acc2[0], 0, 0, 0);
                acc2[1] = __builtin_amdgcn_mfma_f32_32x32x16_f16(af1, bfB[step], acc2[1], 0, 0, 0);
            }
        }
        __syncthreads();                    // all chunk reads done before overwrite
        int l2 = nl;
        int t2 = 2 * r0 - 4 + l2;
        bool valid = (t2 >= 0) && (t2 < T2);
        #pragma unroll
        for (int mi = 0; mi < 2; ++mi)
            #pragma unroll
            for (int q = 0; q < 4; ++q) {
                u16x4 v;
                #pragma unroll
                for (int d = 0; d < 4; ++d) {
                    int o = 32 * mi + 8 * q + 4 * ls + d;
                    float xv = valid ? fmaxf(acc2[mi][4 * q + d] + b2[o], 0.f) : 0.f;
                    v[d] = f2h(xv);
                }
                int gy = 4 * mi + q;
                int sy = gy ^ ((l2 >> 1) & 7);
                *(u16x4*)(sm + l2 * 64 + sy * 8 + ls * 4) = v;
            }
        __syncthreads();
    }

    // ---- Phase C: conv3 MFMA + mean-pool (M=128 x N=256; 2x4 waves of 64x64)
    const int mh = wv & 1, nh = wv >> 1;               // mh 0..1, nh 0..3
    f32x16 acc3[2][2];
    #pragma unroll
    for (int mi = 0; mi < 2; ++mi)
        #pragma unroll
        for (int ni = 0; ni < 2; ++ni)
            #pragma unroll
            for (int q = 0; q < 16; ++q) acc3[mi][ni][q] = 0.f;

    f16x8 bf[2][4];
    #pragma unroll 3
    for (int kk = 0; kk < 9; ++kk) {
        const u16* ap = a3t + kk * 8192;
        {
            #pragma unroll
            for (int ni = 0; ni < 2; ++ni) {
                int nl = 64 * nh + 32 * ni + ln;
                int l2 = 2 * nl + kk;                  // <= 518 < 520
                int rrC = nl + (kk >> 1);
                #pragma unroll
                for (int step = 0; step < 4; ++step) {
                    int sy = (2 * step + ls) ^ (rrC & 7);
                    bf[ni][step] = *(const f16x8*)(sm + l2 * 64 + sy * 8);
                }
            }
        }
        #pragma unroll
        for (int step = 0; step < 4; ++step) {
            f16x8 af0 = *(const f16x8*)(ap + (2 * step + ls) * 1024 + (64 * mh + ln) * 8);
            f16x8 af1 = *(const f16x8*)(ap + (2 * step + ls) * 1024 + (64 * mh + 32 + ln) * 8);
            #pragma unroll
            for (int ni = 0; ni < 2; ++ni) {
                acc3[0][ni] = __builtin_amdgcn_mfma_f32_32x32x16_f16(af0, bf[ni][step], acc3[0][ni], 0, 0, 0);
                acc3[1][ni] = __builtin_amdgcn_mfma_f32_32x32x16_f16(af1, bf[ni][step], acc3[1][ni], 0, 0, 0);
            }
        }
    }

    // epilogue: bias+relu, mask nl>=250, per-wave partials -> LDS reduce -> slot store
    float loc[32];
    #pragma unroll
    for (int mi = 0; mi < 2; ++mi)
        #pragma unroll
        for (int r = 0; r < 16; ++r) {
            int o = 64 * mh + 32 * mi + (r & 3) + 8 * (r >> 2) + 4 * ls;
            float bias = b3[o];
            float s = 0.f;
            #pragma unroll
            for (int ni = 0; ni < 2; ++ni) {
                int nl = 64 * nh + 32 * ni + ln;
                float v = fmaxf(acc3[mi][ni][r] + bias, 0.f);
                s += (nl < NT3) ? v : 0.f;
            }
            loc[mi * 16 + r] = s;
        }
    __syncthreads();
    float* smf = (float*)sm;               // [4 nh][128 o][32 ln] = 64 KB <= 66,560 B
    #pragma unroll
    for (int mi = 0; mi < 2; ++mi)
        #pragma unroll
        for (int r = 0; r < 16; ++r) {
            int o = 64 * mh + 32 * mi + (r & 3) + 8 * (r >> 2) + 4 * ls;
            smf[nh * 4096 + o * 32 + ln] = loc[mi * 16 + r];
        }
    __syncthreads();
    if (tid < 128) {
        int o = tid;
        float s = 0.f;
        #pragma unroll
        for (int j = 0; j < 32; ++j) {
            int col = (j + o) & 31;
            s += smf[o * 32 + col] + smf[4096 + o * 32 + col]
               + smf[8192 + o * 32 + col] + smf[12288 + o * 32 + col];
        }
        // own slot, coalesced, agent scope (sc1 write-through) -> no RMW contention
        __hip_atomic_store(&partials[((size_t)b * NBLKX + blockIdx.x) * 128 + o], s,
                           __ATOMIC_RELAXED, __HIP_MEMORY_SCOPE_AGENT);
    }

    // ---- tail: last block of this batch computes feats (no fence; see header)
    __syncthreads();                        // drains vmcnt(0): slot stores complete
    int* smi = (int*)sm;
    if (tid == 0) {
        int done = atomicAdd(&cnt[b], 1);
        smi[0] = (done == NBLKX - 1) ? 1 : 0;
    }
    __syncthreads();
    if (smi[0]) {
        float* pr = (float*)sm + 64;        // [4][128] cross-slot partial staging
        {
            int o = tid & 127, sub = tid >> 7;     // sub 0..3
            const float* base = partials + (size_t)b * NBLKX * 128 + o;
            float s = 0.f;
            #pragma unroll
            for (int q = 0; q < 8; ++q)
                s += __hip_atomic_load(base + (sub + 4 * q) * 128,
                                       __ATOMIC_RELAXED, __HIP_MEMORY_SCOPE_AGENT);
            pr[sub * 128 + o] = s;
        }
        __syncthreads();
        float* pl = (float*)sm + 64 + 512;  // [128] pooled mean
        float* fl = (float*)sm + 64 + 512 + 128;   // [128] feat staging
        if (tid < 128)
            pl[tid] = (pr[tid] + pr[128 + tid] + pr[256 + tid] + pr[384 + tid])
                      * (1.0f / (float)T3);
        __syncthreads();
        {
            // feats matmul: all 512 threads; 4 threads per output o (i-split 32)
            int o = tid >> 2, sub = tid & 3;
            const float4* wp4 = (const float4*)(wl + o * 128 + sub * 32);
            const float4* pp4 = (const float4*)(pl + sub * 32);
            float s = 0.f;
            #pragma unroll
            for (int q = 0; q < 8; ++q) {
                float4 w4 = wp4[q];
                float4 p4 = pp4[q];
                s += w4.x * p4.x + w4.y * p4.y + w4.z * p4.z + w4.w * p4.w;
            }
            s += __shfl_xor(s, 1);
            s += __shfl_xor(s, 2);
            if (sub == 0) fl[o] = s + bl[o];
        }
        __syncthreads();
        if (tid < 128) {
            float feat = fl[tid];
            if (tid < 64) {                 // wave 0: amps + normalize
                float r = fmaxf(feat, 0.f);
                float ssum = r;
                #pragma unroll
                for (int off = 32; off > 0; off >>= 1) ssum += __shfl_xor(ssum, off);
                featbuf[b * 128 + tid] = r / (ssum + 1e-6f);
            } else {                        // noise_mag raw
                featbuf[b * 128 + tid] = feat;
            }
        }
    }
}

// ---------------- synthesis: Chebyshev sin-recurrence, 4 samples/thread, float4 I/O
// sin(2*pi*(h+1)*u) = 2*cos(2*pi*u)*sin(2*pi*h*u) - sin(2*pi*(h-1)*u)
__global__ __launch_bounds__(256) void synth_k(const float* __restrict__ f0,
                                               const float* __restrict__ wn,
                                               const float* __restrict__ featbuf,
                                               float* __restrict__ out) {
    const int tid = threadIdx.x;
    const int b = blockIdx.y;
    __shared__ float sa[64];
    __shared__ float nm[64];
    if (tid < 64) sa[tid] = featbuf[b * 128 + tid];
    else if (tid < 128) nm[tid - 64] = featbuf[b * 128 + tid];
    __syncthreads();

    const int t0v = blockIdx.x * 1024 + tid * 4;
    if (t0v >= T0) return;                  // tail (after the barrier)

    const float4 fv = *(const float4*)(f0 + (size_t)b * T0 + t0v);
    const float4 wv = *(const float4*)(wn + (size_t)b * T0 + t0v);

    float sc[4], sp[4], tc[4], ac[4];
    #pragma unroll
    for (int s = 0; s < 4; ++s) {
        // u = f0 * t * 4/63999 (linspace incl endpoint); frac in double (phase can
        // reach ~1e5 revolutions), then recurrence runs entirely in fp32.
        double u = (double)((&fv.x)[s]) * ((double)(t0v + s) * (4.0 / 63999.0));
        float uf = (float)(u - floor(u));
        sc[s] = __builtin_amdgcn_sinf(uf);           // sin(2*pi*u)
        tc[s] = 2.0f * __builtin_amdgcn_cosf(uf);    // 2*cos(2*pi*u)
        sp[s] = 0.f;
        ac[s] = 0.f;
    }
    #pragma unroll
    for (int h = 0; h < 64; ++h) {
        float a = sa[h];
        #pragma unroll
        for (int s = 0; s < 4; ++s) {
            ac[s] = fmaf(a, sc[s], ac[s]);
            float sn = fmaf(tc[s], sc[s], -sp[s]);   // sin(2*pi*(h+2)*u)
            sp[s] = sc[s];
            sc[s] = sn;
        }
    }
    float4 o;
    #pragma unroll
    for (int s = 0; s < 4; ++s)
        (&o.x)[s] = ac[s] + (&wv.x)[s] * nm[(t0v + s) / 1000];
    *(float4*)(out + (size_t)b * T0 + t0v) = o;
}

extern "C" void kernel_launch(void* const* d_in, const int* in_sizes, int n_in,
                              void* d_out, int out_size, void* d_ws, size_t ws_size,
                              hipStream_t stream) {
    const float* audio = (const float*)d_in[0];
    const float* f0    = (const float*)d_in[1];
    const float* wn    = (const float*)d_in[2];
    const float* w1    = (const float*)d_in[3];
    const float* b1    = (const float*)d_in[4];
    const float* w2    = (const float*)d_in[5];
    const float* b2    = (const float*)d_in[6];
    const float* w3    = (const float*)d_in[7];
    const float* b3    = (const float*)d_in[8];
    const float* wl    = (const float*)d_in[9];
    const float* bl    = (const float*)d_in[10];
    float* out = (float*)d_out;

    char* ws = (char*)d_ws;
    int*   cnt      = (int*)(ws);                  // 16 int (zeroed by prep_w_k)
    float* featbuf  = (float*)(ws + 1024);         // 2048 f32 (written by mega tail)
    u16*   w1p      = (u16*)(ws + 12288);          // 320 u16 (160 half2)
    u16*   a2t      = (u16*)(ws + 16384);          // 18432 u16
    u16*   a3t      = (u16*)(ws + 16384 + 36864);  // 73728 u16
    float* partials = (float*)(ws + 16384 + 36864 + 147456);  // 512 x 128 f32 = 256 KB

    prep_w_k<<<361, 256, 0, stream>>>(w1, b1, w2, w3, w1p, a2t, a3t, cnt);
    mega_k<<<dim3(NBLKX, BATCH), 512, 0, stream>>>(audio, w1, b1, w1p, a2t, b2, a3t, b3,
                                                   partials, cnt, wl, bl, featbuf);
    synth_k<<<dim3((T0 + 1023) / 1024, BATCH), 256, 0, stream>>>(f0, wn, featbuf, out);
}